// Round 17
// baseline (513.962 us; speedup 1.0000x reference)
//
#include <hip/hip_runtime.h>

typedef unsigned short ushort_t;
typedef unsigned int u32;
typedef __attribute__((ext_vector_type(8))) short bf16x8;
typedef __attribute__((ext_vector_type(8))) unsigned short u16x8;
typedef __attribute__((ext_vector_type(4))) float f32x4;
typedef __attribute__((ext_vector_type(16))) float f32x16;

#define B_ 4
#define S_ 2048
#define D_ 2048
#define H_ 16
#define HD_ 128

__device__ __forceinline__ ushort_t f2bf(float f) {
  u32 x = __builtin_bit_cast(u32, f);
  x += 0x7fffu + ((x >> 16) & 1u);
  return (ushort_t)(x >> 16);
}
__device__ __forceinline__ float bf2f(ushort_t u) {
  u32 x = ((u32)u) << 16;
  return __builtin_bit_cast(float, x);
}

#define GLL16(srcp, ldsp)                                            \
  __builtin_amdgcn_global_load_lds(                                  \
      (const __attribute__((address_space(1))) u32*)(srcp),          \
      (__attribute__((address_space(3))) u32*)(ldsp), 16, 0, 0)

// ---------------- elementwise f32 -> bf16 convert ----------------
struct __align__(8) us4 { ushort_t x, y, z, w; };

__global__ void k_cvt_bf16(const float* __restrict__ in, ushort_t* __restrict__ out, int n) {
  int i = (blockIdx.x * 256 + threadIdx.x) * 4;
  if (i >= n) return;
  float4 v = *(const float4*)(in + i);
  us4 o;
  o.x = f2bf(v.x); o.y = f2bf(v.y); o.z = f2bf(v.z); o.w = f2bf(v.w);
  *(us4*)(out + i) = o;
}

// ---------------- f32 [R][C] -> bf16 [C][R] transpose ----------------
__global__ void k_transpose_bf16(const float* __restrict__ in, ushort_t* __restrict__ out,
                                 int R, int C) {
  __shared__ float ld[32][33];
  int c0 = blockIdx.x * 32, r0 = blockIdx.y * 32;
  int tc = threadIdx.x & 31, tr = threadIdx.x >> 5;
#pragma unroll
  for (int i = 0; i < 4; ++i) {
    int r = tr + i * 8;
    ld[r][tc] = in[(size_t)(r0 + r) * C + c0 + tc];
  }
  __syncthreads();
#pragma unroll
  for (int i = 0; i < 4; ++i) {
    int r = tr + i * 8;
    out[(size_t)(c0 + r) * R + r0 + tc] = f2bf(ld[tc][r]);
  }
}

// ---------------- RoPE cos/sin tables: [S][64] each ----------------
__global__ void k_rope_tables(float* __restrict__ cost, float* __restrict__ sint) {
  int i = blockIdx.x * 256 + threadIdx.x;
  int s = i >> 6, j = i & 63;
  double th = pow(10000.0, -(double)j / 64.0);
  double a = (double)s * th;
  cost[i] = (float)cos(a);
  sint[i] = (float)sin(a);
}

// ---------------- bf16 GEMM: 256x256 tile, 8-phase / 2 K-tiles, 32x32x16 MFMA ----
// (R15 version, unchanged. MODE 1: Q/K slabs + V transposed into Vt.
//  MODE 2: f32 C + bias.)
template <int MODE>
__global__ __launch_bounds__(512) void k_g8(const ushort_t* __restrict__ A,
                                            const ushort_t* __restrict__ Bt,
                                            void* __restrict__ Cout,
                                            const float* __restrict__ bias,
                                            ushort_t* __restrict__ VtB,
                                            int M, int N, int K) {
  __shared__ __attribute__((aligned(16))) ushort_t As[2][256 * 64];  // 64KB
  __shared__ __attribute__((aligned(16))) ushort_t Bs[2][256 * 64];  // 64KB
  const int tid = threadIdx.x;
  const int w = tid >> 6, l = tid & 63;
  const int l31 = l & 31, hl = l >> 5;
  const int wm = w >> 2, wn = w & 3;

  const int cpx = gridDim.x >> 3;
  const int bid = blockIdx.x;
  const int swzid = (bid & 7) * cpx + (bid >> 3);
  const int nbn = N >> 8;
  const size_t m0 = (size_t)(swzid / nbn) * 256;
  const size_t n0 = (size_t)(swzid % nbn) * 256;

  const size_t Kp = (size_t)K * 2;
  const char* Ab = (const char*)A + m0 * Kp;
  const char* Bb = (const char*)Bt + n0 * Kp;

  const int r0 = tid >> 3;
  const int ci16 = (tid & 7) * 16;
  const int sw0 = (((tid & 7) ^ (r0 & 7)) << 4);
  const int sw1 = (((tid & 7) ^ ((r0 + 64) & 7)) << 4);

#define STG_HALF(gbase, hrow, ldsbase, tcol)                                   \
  {                                                                            \
    GLL16((gbase) + (size_t)((hrow) + r0) * Kp + (tcol) + sw0,                 \
          (char*)(ldsbase) + ((hrow) + r0) * 128 + ci16);                      \
    GLL16((gbase) + (size_t)((hrow) + r0 + 64) * Kp + (tcol) + sw1,            \
          (char*)(ldsbase) + ((hrow) + r0 + 64) * 128 + ci16);                 \
  }

  f32x16 acc[4][2] = {};
  const int NI = K >> 7;

  const int arow = wm * 128 + l31;
  const int brow0 = wn * 64 + l31;

  STG_HALF(Ab, 0,   As[0], (size_t)0);
  STG_HALF(Ab, 128, As[0], (size_t)0);
  STG_HALF(Bb, 0,   Bs[0], (size_t)0);
  STG_HALF(Bb, 128, Bs[0], (size_t)0);
  STG_HALF(Bb, 0,   Bs[1], (size_t)128);
  STG_HALF(Bb, 128, Bs[1], (size_t)128);
  asm volatile("s_waitcnt vmcnt(4)");
  __builtin_amdgcn_sched_barrier(0);
  __builtin_amdgcn_s_barrier();

  for (int it = 0; it < NI; ++it) {
    const int t1 = 2 * it + 1;
    const bool more = (it + 1 < NI);
    const size_t cA1 = (size_t)t1 * 128;
    const size_t cT2 = (size_t)(t1 + 1) * 128;
    const size_t cT3 = (size_t)(t1 + 2) * 128;
    bf16x8 bq[2][4];
#pragma unroll
    for (int ph = 0; ph < 8; ++ph) {
      const int slot = ph >> 2;
      const int q = ph & 3;
      const char* Ac = (const char*)As[slot];
      const char* Bc = (const char*)Bs[slot];
      bf16x8 af[4];
      const int ar = arow + q * 32;
#pragma unroll
      for (int ks = 0; ks < 4; ++ks) {
        const int c = ks * 2 + hl;
        af[ks] = *(const bf16x8*)(Ac + ar * 128 + ((c ^ (ar & 7)) << 4));
      }
      if (q == 0) {
#pragma unroll
        for (int nt = 0; nt < 2; ++nt) {
          const int br = brow0 + nt * 32;
#pragma unroll
          for (int ks = 0; ks < 4; ++ks) {
            const int c = ks * 2 + hl;
            bq[nt][ks] = *(const bf16x8*)(Bc + br * 128 + ((c ^ (br & 7)) << 4));
          }
        }
      }
      if (ph == 0)      STG_HALF(Ab, 0,   As[1], cA1)
      else if (ph == 1) STG_HALF(Ab, 128, As[1], cA1)
      else if (ph == 2) { if (more) STG_HALF(Bb, 0,   Bs[0], cT2) }
      else if (ph == 3) { if (more) STG_HALF(Bb, 128, Bs[0], cT2) }
      else if (ph == 4) { if (more) STG_HALF(Ab, 0,   As[0], cT2) }
      else if (ph == 5) { if (more) STG_HALF(Ab, 128, As[0], cT2) }
      else if (ph == 6) { if (more) STG_HALF(Bb, 0,   Bs[1], cT3) }
      else              { if (more) STG_HALF(Bb, 128, Bs[1], cT3) }
      asm volatile("s_waitcnt lgkmcnt(0)");
      __builtin_amdgcn_sched_barrier(0);
      __builtin_amdgcn_s_setprio(1);
#pragma unroll
      for (int ks = 0; ks < 4; ++ks) {
        acc[q][0] = __builtin_amdgcn_mfma_f32_32x32x16_bf16(af[ks], bq[0][ks], acc[q][0], 0, 0, 0);
        acc[q][1] = __builtin_amdgcn_mfma_f32_32x32x16_bf16(af[ks], bq[1][ks], acc[q][1], 0, 0, 0);
      }
      __builtin_amdgcn_s_setprio(0);
      if (ph == 3) {
        if (more) asm volatile("s_waitcnt vmcnt(4)");
        else      asm volatile("s_waitcnt vmcnt(0)");
        __builtin_amdgcn_sched_barrier(0);
      } else if (ph == 7 && more) {
        asm volatile("s_waitcnt vmcnt(4)");
        __builtin_amdgcn_sched_barrier(0);
      }
      __builtin_amdgcn_s_barrier();
    }
  }

  if (MODE == 2) {
#pragma unroll
    for (int nt = 0; nt < 2; ++nt) {
      const size_t col = n0 + wn * 64 + nt * 32 + l31;
      const float bia = bias[col];
#pragma unroll
      for (int mt = 0; mt < 4; ++mt)
#pragma unroll
        for (int r = 0; r < 16; ++r) {
          const size_t row = m0 + wm * 128 + mt * 32 + (r & 3) + 8 * (r >> 2) + 4 * hl;
          ((float*)Cout)[row * N + col] = acc[mt][nt][r] + bia;
        }
    }
  } else {
    ushort_t* Qbase = (ushort_t*)Cout;
#pragma unroll
    for (int nt = 0; nt < 2; ++nt) {
      const int col = (int)n0 + wn * 64 + nt * 32 + l31;
      const int p3 = col >> 11, rem = col & 2047;
      const int h = rem >> 7, d = rem & 127;
      if (p3 < 2) {
        ushort_t* base = Qbase + (size_t)p3 * 16777216ull + (size_t)h * (S_ * HD_) + d;
#pragma unroll
        for (int mt = 0; mt < 4; ++mt)
#pragma unroll
          for (int r = 0; r < 16; ++r) {
            const int row = (int)m0 + wm * 128 + mt * 32 + (r & 3) + 8 * (r >> 2) + 4 * hl;
            const int b2 = row >> 11, s = row & 2047;
            base[(size_t)b2 * (H_ * S_ * HD_) + (size_t)s * HD_] = f2bf(acc[mt][nt][r]);
          }
      } else {
        ushort_t* baseV = VtB + ((size_t)h * HD_ + d) * S_;
#pragma unroll
        for (int mt = 0; mt < 4; ++mt)
#pragma unroll
          for (int r = 0; r < 16; ++r) {
            const int row = (int)m0 + wm * 128 + mt * 32 + (r & 3) + 8 * (r >> 2) + 4 * hl;
            const int b2 = row >> 11, s = row & 2047;
            baseV[(size_t)b2 * ((size_t)H_ * HD_ * S_) + s] = f2bf(acc[mt][nt][r]);
          }
      }
    }
  }
#undef STG_HALF
}

// ---------------- merged in-place RoPE for Q and K slabs ----------------
__global__ void k_rope2(ushort_t* __restrict__ Qr, ushort_t* __restrict__ Kr,
                        const float* __restrict__ cost, const float* __restrict__ sint,
                        float qs) {
  int s0 = blockIdx.x * 32, h = blockIdx.y, z = blockIdx.z;
  const bool isQ = (z < B_);
  const int b = isQ ? z : z - B_;
  const float sc = isQ ? qs : 1.0f;
  ushort_t* t8 = isQ ? Qr : Kr;
  int bh = b * H_ + h;
  const int t = threadIdx.x;
  const int sr = t >> 3, dj = (t & 7) * 8;
  const int s = s0 + sr;
  ushort_t* base = t8 + ((size_t)bh * S_ + s) * HD_;
  u16x8 lo = *(const u16x8*)(base + dj);
  u16x8 hi = *(const u16x8*)(base + 64 + dj);
  const float* cs = cost + s * 64 + dj;
  const float* sn = sint + s * 64 + dj;
  u16x8 olo, ohi;
#pragma unroll
  for (int j = 0; j < 8; ++j) {
    float fl = bf2f(lo[j]), fh = bf2f(hi[j]);
    float c = cs[j], sv = sn[j];
    olo[j] = f2bf((fl * c - fh * sv) * sc);
    ohi[j] = f2bf((fh * c + fl * sv) * sc);
  }
  *(u16x8*)(base + dj) = olo;
  *(u16x8*)(base + 64 + dj) = ohi;
}

// ---------------- causal flash attention v10: QBLK=256, 8 waves ----------------
// vs v9: 512 threads, wave w owns 32 q-rows of a 256-row block -> K/V staging
// per unit work halves; grid = 512 = 2 blocks/XCD-CU-slot with XCD-chunked
// longest-first mapping. LDS 96KB (Ks 32 + Vs 32 + Pl 32) -> 1 block/CU,
// 8 waves resident (same as v9's 2x4). Uniform ledger: 4 loads/thread/tile,
// steady vmcnt(4), tail vmcnt(0). 2 barriers/tile.
__global__ __launch_bounds__(512) void k_attn10(const ushort_t* __restrict__ Q,
                                                const ushort_t* __restrict__ K,
                                                const ushort_t* __restrict__ Vt,
                                                ushort_t* __restrict__ O) {
  __shared__ __attribute__((aligned(16))) ushort_t Ks[2][64 * 128];  // 32KB
  __shared__ __attribute__((aligned(16))) ushort_t Vs[2][128 * 64];  // 32KB
  __shared__ __attribute__((aligned(16))) ushort_t Pl[16][1024];     // 32KB swizzled

  const int id = blockIdx.x;  // 0..511
  const int work = (id & 7) * 64 + (id >> 3);
  const int bh = work >> 3;
  const int qt = 7 - (work & 7);
  const int b = bh >> 4, h = bh & 15;

  const int tid = threadIdx.x;
  const int w = tid >> 6, l = tid & 63;
  const int lr = l & 15, lg = l >> 4;
  const int qb = qt * 256 + w * 32;

  const ushort_t* Qp = Q + (size_t)bh * S_ * HD_;
  const char* Kpb = (const char*)(K + (size_t)bh * S_ * HD_);
  const char* Vpb = (const char*)(Vt + (size_t)bh * HD_ * S_);

  int kr[2], ksz[2], vrw[2], vsz[2];
#pragma unroll
  for (int r = 0; r < 2; ++r) {
    int c = r * 512 + tid;
    kr[r] = c >> 4;
    ksz[r] = (((c & 15) ^ (kr[r] & 15)) << 4);
    vrw[r] = c >> 3;
    vsz[r] = (((c & 7) ^ (vrw[r] & 7)) << 4);
  }

#define STAGE_KV(kb_, bufi)                                                      \
  {                                                                              \
    _Pragma("unroll") for (int r = 0; r < 2; ++r)                                \
        GLL16(Vpb + (size_t)vrw[r] * (S_ * 2) + (size_t)(kb_) * 2 + vsz[r],      \
              (char*)Vs[bufi] + (size_t)(r * 512 + tid) * 16);                   \
    _Pragma("unroll") for (int r = 0; r < 2; ++r)                                \
        GLL16(Kpb + (size_t)((kb_) + kr[r]) * 256 + ksz[r],                      \
              (char*)Ks[bufi] + (size_t)(r * 512 + tid) * 16);                   \
  }

  bf16x8 qf[2][4];
#pragma unroll
  for (int f = 0; f < 2; ++f)
#pragma unroll
    for (int dw = 0; dw < 4; ++dw)
      qf[f][dw] = *(const bf16x8*)(Qp + (size_t)(qb + f * 16 + lr) * HD_ + dw * 32 + lg * 8);

  f32x4 oacc[2][8] = {};
  float lsum[2] = {0.f, 0.f};
  const int nkt = 4 * qt + 4;

  STAGE_KV(0, 0);
  for (int kt = 0; kt < nkt; ++kt) {
    const int kb = kt * 64;
    const int cur = kt & 1;
    const bool morek = (kt + 1 < nkt);
    if (morek) {
      STAGE_KV(kb + 64, cur ^ 1);
      asm volatile("s_waitcnt vmcnt(4)");  // drains {V,K}(t)
    } else {
      asm volatile("s_waitcnt vmcnt(0)");
    }
    __builtin_amdgcn_sched_barrier(0);
    __builtin_amdgcn_s_barrier();  // tile t fully visible

    const bool live = (kb <= qb + 31);
    if (live) {
      const char* Kc = (const char*)Ks[cur];
      const char* Vc = (const char*)Vs[cur];
      // ---- QK^T (swapped) ----
      f32x4 st[2][4];
      __builtin_amdgcn_s_setprio(1);
#pragma unroll
      for (int t = 0; t < 4; ++t) {
        bf16x8 kf[4];
#pragma unroll
        for (int dw = 0; dw < 4; ++dw)
          kf[dw] = *(const bf16x8*)(Kc + (t * 16 + lr) * 256 + (((dw * 4 + lg) ^ lr) << 4));
        f32x4 a0 = {}, a1 = {};
#pragma unroll
        for (int dw = 0; dw < 4; ++dw) {
          a0 = __builtin_amdgcn_mfma_f32_16x16x32_bf16(kf[dw], qf[0][dw], a0, 0, 0, 0);
          a1 = __builtin_amdgcn_mfma_f32_16x16x32_bf16(kf[dw], qf[1][dw], a1, 0, 0, 0);
        }
        st[0][t] = a0;
        st[1][t] = a1;
      }
      __builtin_amdgcn_s_setprio(0);

      // ---- static-base softmax: P = exp2(s) into swizzled Pl ----
#pragma unroll
      for (int f = 0; f < 2; ++f) {
        const int qg = qb + f * 16 + lr;
        const bool full = (kb + 63) <= (qb + f * 16);
        if (!full) {
#pragma unroll
          for (int t = 0; t < 4; ++t)
#pragma unroll
            for (int j = 0; j < 4; ++j) {
              int kg = kb + t * 16 + lg * 4 + j;
              st[f][t][j] = (kg > qg) ? -1e30f : st[f][t][j];
            }
        }
        float psum = 0.f;
        char* Pw = (char*)Pl + (w * 2 + f) * 2048;
#pragma unroll
        for (int t = 0; t < 4; ++t) {
          float p0 = exp2f(st[f][t][0]);
          float p1 = exp2f(st[f][t][1]);
          float p2 = exp2f(st[f][t][2]);
          float p3 = exp2f(st[f][t][3]);
          psum += (p0 + p1) + (p2 + p3);
          u32 pk0, pk1;
          asm("v_cvt_pk_bf16_f32 %0, %1, %2" : "=v"(pk0) : "v"(p0), "v"(p1));
          asm("v_cvt_pk_bf16_f32 %0, %1, %2" : "=v"(pk1) : "v"(p2), "v"(p3));
          const int byt = lr * 128 + (((2 * t + (lg >> 1)) ^ (lr & 7)) << 4) + ((lg & 1) << 3);
          *(u32*)(Pw + byt) = pk0;
          *(u32*)(Pw + byt + 4) = pk1;
        }
        lsum[f] += psum;
      }

      // ---- PV (V resident in LDS; per-wave Pl, no barrier) ----
      const char* Pw0 = (const char*)Pl + (w * 2) * 2048;
      const char* Pw1 = (const char*)Pl + (w * 2 + 1) * 2048;
      __builtin_amdgcn_s_setprio(1);
#pragma unroll
      for (int kw = 0; kw < 2; ++kw) {
        const int pbyt = lr * 128 + (((kw * 4 + lg) ^ (lr & 7)) << 4);
        bf16x8 pa0 = *(const bf16x8*)(Pw0 + pbyt);
        bf16x8 pa1 = *(const bf16x8*)(Pw1 + pbyt);
#pragma unroll
        for (int dt = 0; dt < 8; ++dt) {
          bf16x8 vf = *(const bf16x8*)(Vc + (dt * 16 + lr) * 128 +
                                       (((kw * 4 + lg) ^ (lr & 7)) << 4));
          oacc[0][dt] = __builtin_amdgcn_mfma_f32_16x16x32_bf16(pa0, vf, oacc[0][dt], 0, 0, 0);
          oacc[1][dt] = __builtin_amdgcn_mfma_f32_16x16x32_bf16(pa1, vf, oacc[1][dt], 0, 0, 0);
        }
      }
      __builtin_amdgcn_s_setprio(0);
    }
    __builtin_amdgcn_s_barrier();  // all reads of buf(t) done before next stage
  }

  // ---- epilogue: one butterfly reduce of lsum, then normalize ----
#pragma unroll
  for (int f = 0; f < 2; ++f) {
    lsum[f] += __shfl_xor(lsum[f], 16, 64);
    lsum[f] += __shfl_xor(lsum[f], 32, 64);
    float l0 = __shfl(lsum[f], lg * 4 + 0, 64);
    float l1 = __shfl(lsum[f], lg * 4 + 1, 64);
    float l2 = __shfl(lsum[f], lg * 4 + 2, 64);
    float l3 = __shfl(lsum[f], lg * 4 + 3, 64);
    float i0 = 1.f / l0, i1 = 1.f / l1, i2 = 1.f / l2, i3 = 1.f / l3;
    ushort_t* Op = O + (size_t)(b * S_ + qb + f * 16) * D_ + h * HD_;
#pragma unroll
    for (int dt = 0; dt < 8; ++dt) {
      Op[(size_t)(lg * 4 + 0) * D_ + dt * 16 + lr] = f2bf(oacc[f][dt][0] * i0);
      Op[(size_t)(lg * 4 + 1) * D_ + dt * 16 + lr] = f2bf(oacc[f][dt][1] * i1);
      Op[(size_t)(lg * 4 + 2) * D_ + dt * 16 + lr] = f2bf(oacc[f][dt][2] * i2);
      Op[(size_t)(lg * 4 + 3) * D_ + dt * 16 + lr] = f2bf(oacc[f][dt][3] * i3);
    }
  }
#undef STAGE_KV
}

// ---------------- launch ----------------
extern "C" void kernel_launch(void* const* d_in, const int* in_sizes, int n_in,
                              void* d_out, int out_size, void* d_ws, size_t ws_size,
                              hipStream_t stream) {
  const float* x = (const float*)d_in[0];
  const float* Wqkv = (const float*)d_in[1];
  const float* Wout = (const float*)d_in[2];
  const float* bout = (const float*)d_in[3];
  char* ws = (char*)d_ws;

  ushort_t* xb  = (ushort_t*)(ws + 0);                 // [8192][2048] bf16 -> later O
  ushort_t* Wqt = (ushort_t*)(ws + 33554432ull);       // [6144][2048] bf16
  ushort_t* Qr  = (ushort_t*)(ws + 58720256ull);       // [64][2048][128]
  ushort_t* Kr  = (ushort_t*)(ws + 92274688ull);       // [64][2048][128]
  ushort_t* Vr  = (ushort_t*)(ws + 125829120ull);      // Wout^T region
  ushort_t* Vt  = (ushort_t*)(ws + 159383552ull);      // [64][128][2048]
  float* cost   = (float*)(ws + 192937984ull);         // [2048][64]
  float* sint   = (float*)(ws + 193462272ull);         // [2048][64]

  const int M = B_ * S_;  // 8192
  const float kSc = 0.08838834764831845f * 1.4426950408889634f;  // 1/sqrt(128)*log2e

  k_cvt_bf16<<<dim3((M * D_) / 4 / 256), 256, 0, stream>>>(x, xb, M * D_);
  k_transpose_bf16<<<dim3(3 * D_ / 32, D_ / 32), 256, 0, stream>>>(Wqkv, Wqt, D_, 3 * D_);
  k_rope_tables<<<dim3(S_ * 64 / 256), 256, 0, stream>>>(cost, sint);

  // fused QKV projection: Q/K slabs + V written transposed into Vt
  k_g8<1><<<dim3((M / 256) * (3 * D_ / 256)), 512, 0, stream>>>(
      xb, Wqt, Qr, nullptr, Vt, M, 3 * D_, D_);

  k_rope2<<<dim3(S_ / 32, H_, 2 * B_), 256, 0, stream>>>(Qr, Kr, cost, sint, kSc);

  // Wout^T into Vr region
  k_transpose_bf16<<<dim3(D_ / 32, D_ / 32), 256, 0, stream>>>(Wout, Vr, D_, D_);

  k_attn10<<<dim3((S_ / 256) * B_ * H_), 512, 0, stream>>>(Qr, Kr, Vt, xb /* O */);

  k_g8<2><<<dim3((M / 256) * (D_ / 256)), 512, 0, stream>>>(
      xb, Vr, d_out, bout, nullptr, M, D_, D_);
}

// Round 18
// 483.440 us; speedup vs baseline: 1.0631x; 1.0631x over previous
//
#include <hip/hip_runtime.h>

typedef unsigned short ushort_t;
typedef unsigned int u32;
typedef __attribute__((ext_vector_type(8))) short bf16x8;
typedef __attribute__((ext_vector_type(8))) unsigned short u16x8;
typedef __attribute__((ext_vector_type(4))) float f32x4;
typedef __attribute__((ext_vector_type(16))) float f32x16;

#define B_ 4
#define S_ 2048
#define D_ 2048
#define H_ 16
#define HD_ 128

__device__ __forceinline__ ushort_t f2bf(float f) {
  u32 x = __builtin_bit_cast(u32, f);
  x += 0x7fffu + ((x >> 16) & 1u);
  return (ushort_t)(x >> 16);
}
__device__ __forceinline__ float bf2f(ushort_t u) {
  u32 x = ((u32)u) << 16;
  return __builtin_bit_cast(float, x);
}

#define GLL16(srcp, ldsp)                                            \
  __builtin_amdgcn_global_load_lds(                                  \
      (const __attribute__((address_space(1))) u32*)(srcp),          \
      (__attribute__((address_space(3))) u32*)(ldsp), 16, 0, 0)

// ---------------- elementwise f32 -> bf16 convert ----------------
struct __align__(8) us4 { ushort_t x, y, z, w; };

__global__ void k_cvt_bf16(const float* __restrict__ in, ushort_t* __restrict__ out, int n) {
  int i = (blockIdx.x * 256 + threadIdx.x) * 4;
  if (i >= n) return;
  float4 v = *(const float4*)(in + i);
  us4 o;
  o.x = f2bf(v.x); o.y = f2bf(v.y); o.z = f2bf(v.z); o.w = f2bf(v.w);
  *(us4*)(out + i) = o;
}

// ---------------- f32 [R][C] -> bf16 [C][R] transpose ----------------
__global__ void k_transpose_bf16(const float* __restrict__ in, ushort_t* __restrict__ out,
                                 int R, int C) {
  __shared__ float ld[32][33];
  int c0 = blockIdx.x * 32, r0 = blockIdx.y * 32;
  int tc = threadIdx.x & 31, tr = threadIdx.x >> 5;
#pragma unroll
  for (int i = 0; i < 4; ++i) {
    int r = tr + i * 8;
    ld[r][tc] = in[(size_t)(r0 + r) * C + c0 + tc];
  }
  __syncthreads();
#pragma unroll
  for (int i = 0; i < 4; ++i) {
    int r = tr + i * 8;
    out[(size_t)(c0 + r) * R + r0 + tc] = f2bf(ld[tc][r]);
  }
}

// ---------------- RoPE cos/sin tables: [S][64] each ----------------
__global__ void k_rope_tables(float* __restrict__ cost, float* __restrict__ sint) {
  int i = blockIdx.x * 256 + threadIdx.x;
  int s = i >> 6, j = i & 63;
  double th = pow(10000.0, -(double)j / 64.0);
  double a = (double)s * th;
  cost[i] = (float)cos(a);
  sint[i] = (float)sin(a);
}

// ---------------- bf16 GEMM: 256x256 tile, 8-phase / 2 K-tiles, 32x32x16 MFMA ----
// (R15/R16 version. MODE 1: Q/K slabs + V transposed into Vt. MODE 2: f32 C + bias.)
template <int MODE>
__global__ __launch_bounds__(512) void k_g8(const ushort_t* __restrict__ A,
                                            const ushort_t* __restrict__ Bt,
                                            void* __restrict__ Cout,
                                            const float* __restrict__ bias,
                                            ushort_t* __restrict__ VtB,
                                            int M, int N, int K) {
  __shared__ __attribute__((aligned(16))) ushort_t As[2][256 * 64];  // 64KB
  __shared__ __attribute__((aligned(16))) ushort_t Bs[2][256 * 64];  // 64KB
  const int tid = threadIdx.x;
  const int w = tid >> 6, l = tid & 63;
  const int l31 = l & 31, hl = l >> 5;
  const int wm = w >> 2, wn = w & 3;

  const int cpx = gridDim.x >> 3;
  const int bid = blockIdx.x;
  const int swzid = (bid & 7) * cpx + (bid >> 3);
  const int nbn = N >> 8;
  const size_t m0 = (size_t)(swzid / nbn) * 256;
  const size_t n0 = (size_t)(swzid % nbn) * 256;

  const size_t Kp = (size_t)K * 2;
  const char* Ab = (const char*)A + m0 * Kp;
  const char* Bb = (const char*)Bt + n0 * Kp;

  const int r0 = tid >> 3;
  const int ci16 = (tid & 7) * 16;
  const int sw0 = (((tid & 7) ^ (r0 & 7)) << 4);
  const int sw1 = (((tid & 7) ^ ((r0 + 64) & 7)) << 4);

#define STG_HALF(gbase, hrow, ldsbase, tcol)                                   \
  {                                                                            \
    GLL16((gbase) + (size_t)((hrow) + r0) * Kp + (tcol) + sw0,                 \
          (char*)(ldsbase) + ((hrow) + r0) * 128 + ci16);                      \
    GLL16((gbase) + (size_t)((hrow) + r0 + 64) * Kp + (tcol) + sw1,            \
          (char*)(ldsbase) + ((hrow) + r0 + 64) * 128 + ci16);                 \
  }

  f32x16 acc[4][2] = {};
  const int NI = K >> 7;

  const int arow = wm * 128 + l31;
  const int brow0 = wn * 64 + l31;

  STG_HALF(Ab, 0,   As[0], (size_t)0);
  STG_HALF(Ab, 128, As[0], (size_t)0);
  STG_HALF(Bb, 0,   Bs[0], (size_t)0);
  STG_HALF(Bb, 128, Bs[0], (size_t)0);
  STG_HALF(Bb, 0,   Bs[1], (size_t)128);
  STG_HALF(Bb, 128, Bs[1], (size_t)128);
  asm volatile("s_waitcnt vmcnt(4)");
  __builtin_amdgcn_sched_barrier(0);
  __builtin_amdgcn_s_barrier();

  for (int it = 0; it < NI; ++it) {
    const int t1 = 2 * it + 1;
    const bool more = (it + 1 < NI);
    const size_t cA1 = (size_t)t1 * 128;
    const size_t cT2 = (size_t)(t1 + 1) * 128;
    const size_t cT3 = (size_t)(t1 + 2) * 128;
    bf16x8 bq[2][4];
#pragma unroll
    for (int ph = 0; ph < 8; ++ph) {
      const int slot = ph >> 2;
      const int q = ph & 3;
      const char* Ac = (const char*)As[slot];
      const char* Bc = (const char*)Bs[slot];
      bf16x8 af[4];
      const int ar = arow + q * 32;
#pragma unroll
      for (int ks = 0; ks < 4; ++ks) {
        const int c = ks * 2 + hl;
        af[ks] = *(const bf16x8*)(Ac + ar * 128 + ((c ^ (ar & 7)) << 4));
      }
      if (q == 0) {
#pragma unroll
        for (int nt = 0; nt < 2; ++nt) {
          const int br = brow0 + nt * 32;
#pragma unroll
          for (int ks = 0; ks < 4; ++ks) {
            const int c = ks * 2 + hl;
            bq[nt][ks] = *(const bf16x8*)(Bc + br * 128 + ((c ^ (br & 7)) << 4));
          }
        }
      }
      if (ph == 0)      STG_HALF(Ab, 0,   As[1], cA1)
      else if (ph == 1) STG_HALF(Ab, 128, As[1], cA1)
      else if (ph == 2) { if (more) STG_HALF(Bb, 0,   Bs[0], cT2) }
      else if (ph == 3) { if (more) STG_HALF(Bb, 128, Bs[0], cT2) }
      else if (ph == 4) { if (more) STG_HALF(Ab, 0,   As[0], cT2) }
      else if (ph == 5) { if (more) STG_HALF(Ab, 128, As[0], cT2) }
      else if (ph == 6) { if (more) STG_HALF(Bb, 0,   Bs[1], cT3) }
      else              { if (more) STG_HALF(Bb, 128, Bs[1], cT3) }
      asm volatile("s_waitcnt lgkmcnt(0)");
      __builtin_amdgcn_sched_barrier(0);
      __builtin_amdgcn_s_setprio(1);
#pragma unroll
      for (int ks = 0; ks < 4; ++ks) {
        acc[q][0] = __builtin_amdgcn_mfma_f32_32x32x16_bf16(af[ks], bq[0][ks], acc[q][0], 0, 0, 0);
        acc[q][1] = __builtin_amdgcn_mfma_f32_32x32x16_bf16(af[ks], bq[1][ks], acc[q][1], 0, 0, 0);
      }
      __builtin_amdgcn_s_setprio(0);
      if (ph == 3) {
        if (more) asm volatile("s_waitcnt vmcnt(4)");
        else      asm volatile("s_waitcnt vmcnt(0)");
        __builtin_amdgcn_sched_barrier(0);
      } else if (ph == 7 && more) {
        asm volatile("s_waitcnt vmcnt(4)");
        __builtin_amdgcn_sched_barrier(0);
      }
      __builtin_amdgcn_s_barrier();
    }
  }

  if (MODE == 2) {
#pragma unroll
    for (int nt = 0; nt < 2; ++nt) {
      const size_t col = n0 + wn * 64 + nt * 32 + l31;
      const float bia = bias[col];
#pragma unroll
      for (int mt = 0; mt < 4; ++mt)
#pragma unroll
        for (int r = 0; r < 16; ++r) {
          const size_t row = m0 + wm * 128 + mt * 32 + (r & 3) + 8 * (r >> 2) + 4 * hl;
          ((float*)Cout)[row * N + col] = acc[mt][nt][r] + bia;
        }
    }
  } else {
    ushort_t* Qbase = (ushort_t*)Cout;
#pragma unroll
    for (int nt = 0; nt < 2; ++nt) {
      const int col = (int)n0 + wn * 64 + nt * 32 + l31;
      const int p3 = col >> 11, rem = col & 2047;
      const int h = rem >> 7, d = rem & 127;
      if (p3 < 2) {
        ushort_t* base = Qbase + (size_t)p3 * 16777216ull + (size_t)h * (S_ * HD_) + d;
#pragma unroll
        for (int mt = 0; mt < 4; ++mt)
#pragma unroll
          for (int r = 0; r < 16; ++r) {
            const int row = (int)m0 + wm * 128 + mt * 32 + (r & 3) + 8 * (r >> 2) + 4 * hl;
            const int b2 = row >> 11, s = row & 2047;
            base[(size_t)b2 * (H_ * S_ * HD_) + (size_t)s * HD_] = f2bf(acc[mt][nt][r]);
          }
      } else {
        ushort_t* baseV = VtB + ((size_t)h * HD_ + d) * S_;
#pragma unroll
        for (int mt = 0; mt < 4; ++mt)
#pragma unroll
          for (int r = 0; r < 16; ++r) {
            const int row = (int)m0 + wm * 128 + mt * 32 + (r & 3) + 8 * (r >> 2) + 4 * hl;
            const int b2 = row >> 11, s = row & 2047;
            baseV[(size_t)b2 * ((size_t)H_ * HD_ * S_) + s] = f2bf(acc[mt][nt][r]);
          }
      }
    }
  }
#undef STG_HALF
}

// ---------------- merged in-place RoPE for Q and K slabs ----------------
__global__ void k_rope2(ushort_t* __restrict__ Qr, ushort_t* __restrict__ Kr,
                        const float* __restrict__ cost, const float* __restrict__ sint,
                        float qs) {
  int s0 = blockIdx.x * 32, h = blockIdx.y, z = blockIdx.z;
  const bool isQ = (z < B_);
  const int b = isQ ? z : z - B_;
  const float sc = isQ ? qs : 1.0f;
  ushort_t* t8 = isQ ? Qr : Kr;
  int bh = b * H_ + h;
  const int t = threadIdx.x;
  const int sr = t >> 3, dj = (t & 7) * 8;
  const int s = s0 + sr;
  ushort_t* base = t8 + ((size_t)bh * S_ + s) * HD_;
  u16x8 lo = *(const u16x8*)(base + dj);
  u16x8 hi = *(const u16x8*)(base + 64 + dj);
  const float* cs = cost + s * 64 + dj;
  const float* sn = sint + s * 64 + dj;
  u16x8 olo, ohi;
#pragma unroll
  for (int j = 0; j < 8; ++j) {
    float fl = bf2f(lo[j]), fh = bf2f(hi[j]);
    float c = cs[j], sv = sn[j];
    olo[j] = f2bf((fl * c - fh * sv) * sc);
    ohi[j] = f2bf((fh * c + fl * sv) * sc);
  }
  *(u16x8*)(base + dj) = olo;
  *(u16x8*)(base + 64 + dj) = ohi;
}

// ---------------- causal flash attention v9 (R16, proven best) ----------------
__global__ __launch_bounds__(256, 2) void k_attn9(const ushort_t* __restrict__ Q,
                                                  const ushort_t* __restrict__ K,
                                                  const ushort_t* __restrict__ Vt,
                                                  ushort_t* __restrict__ O) {
  __shared__ __attribute__((aligned(16))) ushort_t Ks[2][64 * 128];  // 32KB
  __shared__ __attribute__((aligned(16))) ushort_t Vs[2][128 * 64];  // 32KB
  __shared__ __attribute__((aligned(16))) ushort_t Pl[8][1024];      // 16KB swizzled

  const int id = blockIdx.x;  // 0..1023
  const int work = (id & 7) * 128 + (id >> 3);
  const int bh = work >> 4;
  const int qt = 15 - (work & 15);
  const int b = bh >> 4, h = bh & 15;

  const int tid = threadIdx.x;
  const int w = tid >> 6, l = tid & 63;
  const int lr = l & 15, lg = l >> 4;
  const int qb = qt * 128 + w * 32;

  const ushort_t* Qp = Q + (size_t)bh * S_ * HD_;
  const char* Kpb = (const char*)(K + (size_t)bh * S_ * HD_);
  const char* Vpb = (const char*)(Vt + (size_t)bh * HD_ * S_);

  int kr[4], ksz[4], vrw[4], vsz[4];
#pragma unroll
  for (int r = 0; r < 4; ++r) {
    int c = r * 256 + tid;
    kr[r] = c >> 4;
    ksz[r] = (((c & 15) ^ (kr[r] & 15)) << 4);
    vrw[r] = c >> 3;
    vsz[r] = (((c & 7) ^ (vrw[r] & 7)) << 4);
  }

#define STAGE_KV(kb_, bufi)                                                      \
  {                                                                              \
    _Pragma("unroll") for (int r = 0; r < 4; ++r)                                \
        GLL16(Vpb + (size_t)vrw[r] * (S_ * 2) + (size_t)(kb_) * 2 + vsz[r],      \
              (char*)Vs[bufi] + (size_t)(r * 256 + tid) * 16);                   \
    _Pragma("unroll") for (int r = 0; r < 4; ++r)                                \
        GLL16(Kpb + (size_t)((kb_) + kr[r]) * 256 + ksz[r],                      \
              (char*)Ks[bufi] + (size_t)(r * 256 + tid) * 16);                   \
  }

  bf16x8 qf[2][4];
#pragma unroll
  for (int f = 0; f < 2; ++f)
#pragma unroll
    for (int dw = 0; dw < 4; ++dw)
      qf[f][dw] = *(const bf16x8*)(Qp + (size_t)(qb + f * 16 + lr) * HD_ + dw * 32 + lg * 8);

  f32x4 oacc[2][8] = {};
  float lsum[2] = {0.f, 0.f};
  const int nkt = 2 * qt + 2;

  STAGE_KV(0, 0);
  for (int kt = 0; kt < nkt; ++kt) {
    const int kb = kt * 64;
    const int cur = kt & 1;
    const bool morek = (kt + 1 < nkt);
    if (morek) {
      STAGE_KV(kb + 64, cur ^ 1);
      asm volatile("s_waitcnt vmcnt(8)");  // drains {V,K}(t)
    } else {
      asm volatile("s_waitcnt vmcnt(0)");
    }
    __builtin_amdgcn_sched_barrier(0);
    __builtin_amdgcn_s_barrier();  // tile t fully visible

    const bool live = (kb <= qb + 31);
    if (live) {
      const char* Kc = (const char*)Ks[cur];
      const char* Vc = (const char*)Vs[cur];
      // ---- QK^T (swapped) ----
      f32x4 st[2][4];
      __builtin_amdgcn_s_setprio(1);
#pragma unroll
      for (int t = 0; t < 4; ++t) {
        bf16x8 kf[4];
#pragma unroll
        for (int dw = 0; dw < 4; ++dw)
          kf[dw] = *(const bf16x8*)(Kc + (t * 16 + lr) * 256 + (((dw * 4 + lg) ^ lr) << 4));
        f32x4 a0 = {}, a1 = {};
#pragma unroll
        for (int dw = 0; dw < 4; ++dw) {
          a0 = __builtin_amdgcn_mfma_f32_16x16x32_bf16(kf[dw], qf[0][dw], a0, 0, 0, 0);
          a1 = __builtin_amdgcn_mfma_f32_16x16x32_bf16(kf[dw], qf[1][dw], a1, 0, 0, 0);
        }
        st[0][t] = a0;
        st[1][t] = a1;
      }
      __builtin_amdgcn_s_setprio(0);

      // ---- static-base softmax: P = exp2(s) into swizzled Pl ----
#pragma unroll
      for (int f = 0; f < 2; ++f) {
        const int qg = qb + f * 16 + lr;
        const bool full = (kb + 63) <= (qb + f * 16);
        if (!full) {
#pragma unroll
          for (int t = 0; t < 4; ++t)
#pragma unroll
            for (int j = 0; j < 4; ++j) {
              int kg = kb + t * 16 + lg * 4 + j;
              st[f][t][j] = (kg > qg) ? -1e30f : st[f][t][j];
            }
        }
        float psum = 0.f;
        char* Pw = (char*)Pl + (w * 2 + f) * 2048;
#pragma unroll
        for (int t = 0; t < 4; ++t) {
          float p0 = exp2f(st[f][t][0]);
          float p1 = exp2f(st[f][t][1]);
          float p2 = exp2f(st[f][t][2]);
          float p3 = exp2f(st[f][t][3]);
          psum += (p0 + p1) + (p2 + p3);
          u32 pk0, pk1;
          asm("v_cvt_pk_bf16_f32 %0, %1, %2" : "=v"(pk0) : "v"(p0), "v"(p1));
          asm("v_cvt_pk_bf16_f32 %0, %1, %2" : "=v"(pk1) : "v"(p2), "v"(p3));
          const int byt = lr * 128 + (((2 * t + (lg >> 1)) ^ (lr & 7)) << 4) + ((lg & 1) << 3);
          *(u32*)(Pw + byt) = pk0;
          *(u32*)(Pw + byt + 4) = pk1;
        }
        lsum[f] += psum;
      }

      // ---- PV (V already resident; per-wave Pl, no barrier) ----
      const char* Pw0 = (const char*)Pl + (w * 2) * 2048;
      const char* Pw1 = (const char*)Pl + (w * 2 + 1) * 2048;
      __builtin_amdgcn_s_setprio(1);
#pragma unroll
      for (int kw = 0; kw < 2; ++kw) {
        const int pbyt = lr * 128 + (((kw * 4 + lg) ^ (lr & 7)) << 4);
        bf16x8 pa0 = *(const bf16x8*)(Pw0 + pbyt);
        bf16x8 pa1 = *(const bf16x8*)(Pw1 + pbyt);
#pragma unroll
        for (int dt = 0; dt < 8; ++dt) {
          bf16x8 vf = *(const bf16x8*)(Vc + (dt * 16 + lr) * 128 +
                                       (((kw * 4 + lg) ^ (lr & 7)) << 4));
          oacc[0][dt] = __builtin_amdgcn_mfma_f32_16x16x32_bf16(pa0, vf, oacc[0][dt], 0, 0, 0);
          oacc[1][dt] = __builtin_amdgcn_mfma_f32_16x16x32_bf16(pa1, vf, oacc[1][dt], 0, 0, 0);
        }
      }
      __builtin_amdgcn_s_setprio(0);
    }
    __builtin_amdgcn_s_barrier();  // all reads of buf(t) done before next stage
  }

  // ---- epilogue: one butterfly reduce of lsum, then normalize ----
#pragma unroll
  for (int f = 0; f < 2; ++f) {
    lsum[f] += __shfl_xor(lsum[f], 16, 64);
    lsum[f] += __shfl_xor(lsum[f], 32, 64);
    float l0 = __shfl(lsum[f], lg * 4 + 0, 64);
    float l1 = __shfl(lsum[f], lg * 4 + 1, 64);
    float l2 = __shfl(lsum[f], lg * 4 + 2, 64);
    float l3 = __shfl(lsum[f], lg * 4 + 3, 64);
    float i0 = 1.f / l0, i1 = 1.f / l1, i2 = 1.f / l2, i3 = 1.f / l3;
    ushort_t* Op = O + (size_t)(b * S_ + qb + f * 16) * D_ + h * HD_;
#pragma unroll
    for (int dt = 0; dt < 8; ++dt) {
      Op[(size_t)(lg * 4 + 0) * D_ + dt * 16 + lr] = f2bf(oacc[f][dt][0] * i0);
      Op[(size_t)(lg * 4 + 1) * D_ + dt * 16 + lr] = f2bf(oacc[f][dt][1] * i1);
      Op[(size_t)(lg * 4 + 2) * D_ + dt * 16 + lr] = f2bf(oacc[f][dt][2] * i2);
      Op[(size_t)(lg * 4 + 3) * D_ + dt * 16 + lr] = f2bf(oacc[f][dt][3] * i3);
    }
  }
#undef STAGE_KV
}

// ---------------- launch ----------------
extern "C" void kernel_launch(void* const* d_in, const int* in_sizes, int n_in,
                              void* d_out, int out_size, void* d_ws, size_t ws_size,
                              hipStream_t stream) {
  const float* x = (const float*)d_in[0];
  const float* Wqkv = (const float*)d_in[1];
  const float* Wout = (const float*)d_in[2];
  const float* bout = (const float*)d_in[3];
  char* ws = (char*)d_ws;

  ushort_t* xb  = (ushort_t*)(ws + 0);                 // [8192][2048] bf16 -> later O
  ushort_t* Wqt = (ushort_t*)(ws + 33554432ull);       // [6144][2048] bf16
  ushort_t* Qr  = (ushort_t*)(ws + 58720256ull);       // [64][2048][128]
  ushort_t* Kr  = (ushort_t*)(ws + 92274688ull);       // [64][2048][128]
  ushort_t* Vr  = (ushort_t*)(ws + 125829120ull);      // Wout^T region
  ushort_t* Vt  = (ushort_t*)(ws + 159383552ull);      // [64][128][2048]
  float* cost   = (float*)(ws + 192937984ull);         // [2048][64]
  float* sint   = (float*)(ws + 193462272ull);         // [2048][64]

  const int M = B_ * S_;  // 8192
  const float kSc = 0.08838834764831845f * 1.4426950408889634f;  // 1/sqrt(128)*log2e

  k_cvt_bf16<<<dim3((M * D_) / 4 / 256), 256, 0, stream>>>(x, xb, M * D_);
  k_transpose_bf16<<<dim3(3 * D_ / 32, D_ / 32), 256, 0, stream>>>(Wqkv, Wqt, D_, 3 * D_);
  k_rope_tables<<<dim3(S_ * 64 / 256), 256, 0, stream>>>(cost, sint);

  // fused QKV projection: Q/K slabs + V written transposed into Vt
  k_g8<1><<<dim3((M / 256) * (3 * D_ / 256)), 512, 0, stream>>>(
      xb, Wqt, Qr, nullptr, Vt, M, 3 * D_, D_);

  k_rope2<<<dim3(S_ / 32, H_, 2 * B_), 256, 0, stream>>>(Qr, Kr, cost, sint, kSc);

  // Wout^T into Vr region
  k_transpose_bf16<<<dim3(D_ / 32, D_ / 32), 256, 0, stream>>>(Wout, Vr, D_, D_);

  k_attn9<<<dim3((S_ / 128) * B_ * H_), 256, 0, stream>>>(Qr, Kr, Vt, xb /* O */);

  k_g8<2><<<dim3((M / 256) * (D_ / 256)), 512, 0, stream>>>(
      xb, Vr, d_out, bout, nullptr, M, D_, D_);
}